// Round 6
// baseline (95.954 us; speedup 1.0000x reference)
//
#include <hip/hip_runtime.h>
#include <math.h>

#define BB 32
#define CC 768
#define HID 96
#define NPIX 1024
#define KSEL 256
#define BN_EPS_F 1e-5f

typedef __bf16 bf16x8 __attribute__((ext_vector_type(8)));
typedef float f32x4 __attribute__((ext_vector_type(4)));

__device__ __forceinline__ unsigned short f2bf(float f) {
    unsigned u = __float_as_uint(f);
    return (unsigned short)((u + 0x7FFFu + ((u >> 16) & 1u)) >> 16);  // RNE
}
__device__ __forceinline__ unsigned pack2(float lo, float hi) {
    return (unsigned)f2bf(lo) | ((unsigned)f2bf(hi) << 16);
}

// ---------------------------------------------------------------------------
// K0: prep — w1 f32 -> bf16 [96][768]; BN scale/shift [96]. grid 73 x 256.
// ---------------------------------------------------------------------------
__global__ __launch_bounds__(256) void k0_prep(
    const float* __restrict__ w1, const float* __restrict__ gamma,
    const float* __restrict__ beta, const float* __restrict__ mean,
    const float* __restrict__ var,
    unsigned short* __restrict__ w1b, float* __restrict__ scale,
    float* __restrict__ shift)
{
    int t = threadIdx.x, bk = blockIdx.x;
    if (bk < 72) {
        int idx = (bk * 256 + t) * 4;
        float4 v = *reinterpret_cast<const float4*>(w1 + idx);
        uint2 o;
        o.x = pack2(v.x, v.y);
        o.y = pack2(v.z, v.w);
        *reinterpret_cast<uint2*>(w1b + idx) = o;
    } else if (t < HID) {
        float sc = gamma[t] * rsqrtf(var[t] + BN_EPS_F);
        scale[t] = sc;
        shift[t] = beta[t] - mean[t] * sc;
    }
}

// ---------------------------------------------------------------------------
// K1 v3: bf16 MFMA GEMM  H[o,n] = sum_c w1[o,c]*x[b,c,n], fused BN+ReLU.
// grid (16 n-tiles of 64, 32 b) = 512 blocks (2/CU), 512 thr = 8 waves
// (4 waves/SIMD). Wave (wo,wn) owns 48o x 16n; acc = 3 f32x4 only.
// W1 fragments REGISTER double-buffered from global (prefetched one full
// chunk ahead -> latency hidden; no W LDS, no W bank conflicts).
// X chunk (64c x 64n) in LDS, pad 66 (2-way max on write+read), reg-staged
// issue-early/write-late, ONE barrier per chunk. 2x-unrolled named bufs.
// ---------------------------------------------------------------------------
__global__ __launch_bounds__(512, 4) void k1_gemm_mfma(
    const float* __restrict__ x, const unsigned short* __restrict__ w1b,
    const float* __restrict__ scale, const float* __restrict__ shift,
    float* __restrict__ h_out)
{
    __shared__ unsigned Xs[2][32][66];   // [buf][kpair][n] uint = 2 bf16
    __shared__ float sc_s[HID], sh_s[HID];

    const int t = threadIdx.x;
    const int b = blockIdx.y;
    const int n0 = blockIdx.x * 64;
    const int wave = t >> 6, lane = t & 63;
    const int lm = lane & 15, g = lane >> 4;
    const int wo = wave >> 2, wn = wave & 3;
    const int nB = wn * 16 + lm;          // B-frag column within tile
    const int kp = t >> 4, q = t & 15;    // staging: kpair, col group
    const int nc = q * 4;

    if (t < HID) { sc_s[t] = scale[t]; sh_s[t] = shift[t]; }

    f32x4 acc[3];
#pragma unroll
    for (int mt = 0; mt < 3; ++mt) acc[mt] = (f32x4){0.f, 0.f, 0.f, 0.f};

    const float* xbase = x + (size_t)b * CC * NPIX + n0;
    const unsigned short* wrow = w1b + (size_t)(wo * 48 + lm) * CC;

    uint4 wA[6], wB[6];

    // ---- prologue: stage X chunk0 -> buf0; load wA(chunk0) ----
    {
        const float* r0 = xbase + (size_t)(2 * kp) * NPIX;
        float4 a4 = *reinterpret_cast<const float4*>(r0 + nc);
        float4 b4 = *reinterpret_cast<const float4*>(r0 + NPIX + nc);
        uint4 pk;
        pk.x = pack2(a4.x, b4.x); pk.y = pack2(a4.y, b4.y);
        pk.z = pack2(a4.z, b4.z); pk.w = pack2(a4.w, b4.w);
        *reinterpret_cast<uint4*>(&Xs[0][kp][nc]) = pk;
#pragma unroll
        for (int mt = 0; mt < 3; ++mt)
#pragma unroll
            for (int h = 0; h < 2; ++h)
                wA[mt * 2 + h] = *reinterpret_cast<const uint4*>(
                    wrow + (size_t)mt * 16 * CC + h * 32 + g * 8);
    }
    __syncthreads();

#pragma unroll 1
    for (int j = 0; j < 6; ++j) {
        const int cA = 2 * j * 64;          // chunk in buf0 with wA
        const int cB = cA + 64;             // chunk in buf1 with wB
        // ======== phase A: compute chunk cA, stage cB ========
        {
            const float* r0 = xbase + (size_t)(cB + 2 * kp) * NPIX;
            float4 a4 = *reinterpret_cast<const float4*>(r0 + nc);
            float4 b4 = *reinterpret_cast<const float4*>(r0 + NPIX + nc);
#pragma unroll
            for (int mt = 0; mt < 3; ++mt)
#pragma unroll
                for (int h = 0; h < 2; ++h)
                    wB[mt * 2 + h] = *reinterpret_cast<const uint4*>(
                        wrow + (size_t)mt * 16 * CC + cB + h * 32 + g * 8);
#pragma unroll
            for (int h = 0; h < 2; ++h) {
                uint4 bu;
                bu.x = Xs[0][16 * h + 4 * g + 0][nB];
                bu.y = Xs[0][16 * h + 4 * g + 1][nB];
                bu.z = Xs[0][16 * h + 4 * g + 2][nB];
                bu.w = Xs[0][16 * h + 4 * g + 3][nB];
                bf16x8 bfr = __builtin_bit_cast(bf16x8, bu);
#pragma unroll
                for (int mt = 0; mt < 3; ++mt)
                    acc[mt] = __builtin_amdgcn_mfma_f32_16x16x32_bf16(
                        __builtin_bit_cast(bf16x8, wA[mt * 2 + h]), bfr, acc[mt], 0, 0, 0);
            }
            uint4 pk;
            pk.x = pack2(a4.x, b4.x); pk.y = pack2(a4.y, b4.y);
            pk.z = pack2(a4.z, b4.z); pk.w = pack2(a4.w, b4.w);
            *reinterpret_cast<uint4*>(&Xs[1][kp][nc]) = pk;
        }
        __syncthreads();
        // ======== phase B: compute chunk cB, stage cA+128 ========
        {
            const bool hasNext = (j < 5);
            float4 a4, b4;
            if (hasNext) {
                const float* r0 = xbase + (size_t)(cB + 64 + 2 * kp) * NPIX;
                a4 = *reinterpret_cast<const float4*>(r0 + nc);
                b4 = *reinterpret_cast<const float4*>(r0 + NPIX + nc);
#pragma unroll
                for (int mt = 0; mt < 3; ++mt)
#pragma unroll
                    for (int h = 0; h < 2; ++h)
                        wA[mt * 2 + h] = *reinterpret_cast<const uint4*>(
                            wrow + (size_t)mt * 16 * CC + cB + 64 + h * 32 + g * 8);
            }
#pragma unroll
            for (int h = 0; h < 2; ++h) {
                uint4 bu;
                bu.x = Xs[1][16 * h + 4 * g + 0][nB];
                bu.y = Xs[1][16 * h + 4 * g + 1][nB];
                bu.z = Xs[1][16 * h + 4 * g + 2][nB];
                bu.w = Xs[1][16 * h + 4 * g + 3][nB];
                bf16x8 bfr = __builtin_bit_cast(bf16x8, bu);
#pragma unroll
                for (int mt = 0; mt < 3; ++mt)
                    acc[mt] = __builtin_amdgcn_mfma_f32_16x16x32_bf16(
                        __builtin_bit_cast(bf16x8, wB[mt * 2 + h]), bfr, acc[mt], 0, 0, 0);
            }
            if (hasNext) {
                uint4 pk;
                pk.x = pack2(a4.x, b4.x); pk.y = pack2(a4.y, b4.y);
                pk.z = pack2(a4.z, b4.z); pk.w = pack2(a4.w, b4.w);
                *reinterpret_cast<uint4*>(&Xs[0][kp][nc]) = pk;
                __syncthreads();
            }
        }
    }

    // epilogue: C/D col = lm (n), row = g*4+r (o); BN+ReLU
#pragma unroll
    for (int mt = 0; mt < 3; ++mt) {
#pragma unroll
        for (int r = 0; r < 4; ++r) {
            int o = wo * 48 + mt * 16 + g * 4 + r;
            float v = fmaxf(acc[mt][r] * sc_s[o] + sh_s[o], 0.f);
            h_out[((size_t)b * HID + o) * NPIX + n0 + nB] = v;
        }
    }
}

// ---------------------------------------------------------------------------
// K2: 3x3 conv HID->1, SAME. grid (8 y-tiles of 4 rows, 32 b) = 256 blocks,
// 128 thr (1 px/thread). 16-channel LDS chunks with row halo.
// ---------------------------------------------------------------------------
__global__ __launch_bounds__(128) void k2_conv3x3(
    const float* __restrict__ h_in, const float* __restrict__ w2,
    const float* __restrict__ b2, float* __restrict__ score_out)
{
    __shared__ float hs[16][6][40];   // interior cols 4..35; halo cols 3 and 36
    __shared__ float w2s[HID * 9];

    const int t = threadIdx.x;
    const int ytile = blockIdx.x, b = blockIdx.y;
    const int y = t >> 5, xx = t & 31;
    const int Y = ytile * 4 + y;

    for (int i = t; i < HID * 9; i += 128) w2s[i] = w2[i];

    const float* hb = h_in + (size_t)b * HID * NPIX;
    float acc = 0.f;

    for (int c0 = 0; c0 < HID; c0 += 16) {
        __syncthreads();
        for (int i = t; i < 192; i += 128) {  // zero halo cols (3 and 36)
            int ch = i / 12, rr = (i % 12) >> 1, col = (i & 1) ? 36 : 3;
            hs[ch][rr][col] = 0.f;
        }
#pragma unroll
        for (int i = 0; i < 6; ++i) {
            int idx = t + i * 128;               // 0..767 float4 slots
            int ch = idx / 48, rem = idx % 48;
            int rr = rem >> 3, qq = rem & 7;
            int gy = ytile * 4 - 1 + rr;
            float4 v = (gy >= 0 && gy < 32)
                ? *reinterpret_cast<const float4*>(
                      hb + (size_t)(c0 + ch) * NPIX + gy * 32 + qq * 4)
                : (float4){0.f, 0.f, 0.f, 0.f};
            *reinterpret_cast<float4*>(&hs[ch][rr][4 + qq * 4]) = v;
        }
        __syncthreads();
#pragma unroll
        for (int ch = 0; ch < 16; ++ch) {
            float s = 0.f;
#pragma unroll
            for (int ky = 0; ky < 3; ++ky)
#pragma unroll
                for (int kx = 0; kx < 3; ++kx)
                    s += hs[ch][y + ky][3 + xx + kx] * w2s[(c0 + ch) * 9 + ky * 3 + kx];
            acc += s;
        }
    }
    score_out[b * NPIX + Y * 32 + xx] = acc + b2[0];
}

// ---------------------------------------------------------------------------
// K3: exact top-256 (radix select, first-index tie-break) + softmax ->
// dense weight[1024]. grid 32, 256 thr; elements register-resident (4/thr).
// ---------------------------------------------------------------------------
__global__ __launch_bounds__(256) void k3_topk_softmax(
    const float* __restrict__ score, float* __restrict__ weight)
{
    __shared__ unsigned hist[256];
    __shared__ unsigned wtot[4];
    __shared__ unsigned pcnt16[16];
    __shared__ float redf[4];
    __shared__ unsigned sh_bin, sh_rem;

    const int t = threadIdx.x, b = blockIdx.x;
    const int lane = t & 63, wv = t >> 6;

    float fvals[4];
    unsigned uvals[4];
#pragma unroll
    for (int i = 0; i < 4; ++i) {
        float f = score[b * NPIX + t + 256 * i];
        fvals[i] = f;
        unsigned u = __float_as_uint(f);
        uvals[i] = (u & 0x80000000u) ? ~u : (u | 0x80000000u);
    }

    unsigned prefix = 0, rem = KSEL;
    for (int p = 3; p >= 0; --p) {
        hist[t] = 0;
        __syncthreads();
        const int sh_hi = (p + 1) * 8;
#pragma unroll
        for (int i = 0; i < 4; ++i) {
            unsigned u = uvals[i];
            bool match = (p == 3) || ((u >> sh_hi) == (prefix >> sh_hi));
            if (match) atomicAdd(&hist[(u >> (p * 8)) & 0xffu], 1u);
        }
        __syncthreads();
        unsigned own = hist[t];
        unsigned val = own;
#pragma unroll
        for (int off = 1; off <= 32; off <<= 1) {
            unsigned o2 = __shfl_down(val, off);
            if (lane + off < 64) val += o2;
        }
        if (lane == 0) wtot[wv] = val;
        __syncthreads();
        unsigned suff = val;
        for (int w = wv + 1; w < 4; ++w) suff += wtot[w];
        unsigned nexts = suff - own;        // count with bin > t
        if (suff >= rem && nexts < rem) { sh_bin = (unsigned)t; sh_rem = rem - nexts; }
        __syncthreads();
        prefix |= (sh_bin << (p * 8));
        rem = sh_rem;
        __syncthreads();
    }
    const unsigned T = prefix, need = rem;

    float m = -INFINITY;
#pragma unroll
    for (int i = 0; i < 4; ++i) m = fmaxf(m, fvals[i]);
#pragma unroll
    for (int off = 32; off >= 1; off >>= 1) m = fmaxf(m, __shfl_xor(m, off));
    if (lane == 0) redf[wv] = m;
    __syncthreads();
    m = fmaxf(fmaxf(redf[0], redf[1]), fmaxf(redf[2], redf[3]));

    unsigned lp[4]; bool eqf[4], gtf[4];
    unsigned long long lmask = (1ULL << lane) - 1ULL;
#pragma unroll
    for (int i = 0; i < 4; ++i) {
        bool eq = (uvals[i] == T);
        eqf[i] = eq; gtf[i] = (uvals[i] > T);
        unsigned long long mk = __ballot(eq);
        lp[i] = (unsigned)__popcll(mk & lmask);
        if (lane == 0) pcnt16[i * 4 + wv] = (unsigned)__popcll(mk);
    }
    __syncthreads();
    unsigned cum = 0, baseArr[4];
#pragma unroll
    for (int ii = 0; ii < 4; ++ii) {
        unsigned b0 = cum;
        for (int w = 0; w < wv; ++w) b0 += pcnt16[ii * 4 + w];
        baseArr[ii] = b0;
        for (int w = 0; w < 4; ++w) cum += pcnt16[ii * 4 + w];
    }
    float evals[4], sumExp = 0.f;
#pragma unroll
    for (int i = 0; i < 4; ++i) {
        bool sel = gtf[i] || (eqf[i] && (baseArr[i] + lp[i]) < need);
        float e = sel ? expf(fvals[i] - m) : 0.f;
        evals[i] = e;
        sumExp += e;
    }
#pragma unroll
    for (int off = 32; off >= 1; off >>= 1) sumExp += __shfl_xor(sumExp, off);
    if (lane == 0) redf[wv] = sumExp;
    __syncthreads();
    float inv = 1.0f / (redf[0] + redf[1] + redf[2] + redf[3]);
#pragma unroll
    for (int i = 0; i < 4; ++i)
        weight[b * NPIX + i * 256 + t] = evals[i] * inv;
}

// ---------------------------------------------------------------------------
// K4: v[b,c] = sum_n x[b,c,n]*weight[b,n]. grid 32*192, 4 waves, 1 c/wave.
// ---------------------------------------------------------------------------
__global__ __launch_bounds__(256) void k4_weighted_sum(
    const float* __restrict__ x, const float* __restrict__ weight,
    float* __restrict__ v)
{
    __shared__ float wsm[NPIX];
    const int t = threadIdx.x;
    const int b = blockIdx.x / 192, cg = blockIdx.x % 192;

    *reinterpret_cast<float4*>(&wsm[t * 4]) =
        *reinterpret_cast<const float4*>(&weight[b * NPIX + t * 4]);
    __syncthreads();

    const int lane = t & 63, wvv = t >> 6;
    const int c = cg * 4 + wvv;
    const float* xr = x + ((size_t)b * CC + c) * NPIX;

    float acc = 0.f;
#pragma unroll
    for (int j = 0; j < 4; ++j) {
        int off = j * 256 + lane * 4;
        float4 xv = *reinterpret_cast<const float4*>(xr + off);
        float4 wv4 = *reinterpret_cast<const float4*>(&wsm[off]);
        acc += xv.x * wv4.x + xv.y * wv4.y + xv.z * wv4.z + xv.w * wv4.w;
    }
#pragma unroll
    for (int off = 32; off >= 1; off >>= 1) acc += __shfl_xor(acc, off);
    if (lane == 0) v[(size_t)b * CC + c] = acc;
}

// ---------------------------------------------------------------------------
extern "C" void kernel_launch(void* const* d_in, const int* in_sizes, int n_in,
                              void* d_out, int out_size, void* d_ws, size_t ws_size,
                              hipStream_t stream)
{
    const float* x     = (const float*)d_in[0];
    const float* w1    = (const float*)d_in[1];
    const float* gamma = (const float*)d_in[2];
    const float* beta  = (const float*)d_in[3];
    const float* mean  = (const float*)d_in[4];
    const float* var   = (const float*)d_in[5];
    const float* w2    = (const float*)d_in[6];
    const float* b2    = (const float*)d_in[7];

    float* out   = (float*)d_out;
    float* vout  = out;                  // [32,768]
    float* score = out + BB * CC;        // [32,1024]

    float* h       = (float*)d_ws;                                // 32*96*1024 f32
    float* weight  = h + (size_t)BB * HID * NPIX;                 // 32*1024 f32
    unsigned short* w1b = (unsigned short*)(weight + BB * NPIX);  // 96*768 bf16
    float* scale   = (float*)(w1b + HID * CC);                    // 96
    float* shift   = scale + HID;                                 // 96

    k0_prep<<<73, 256, 0, stream>>>(w1, gamma, beta, mean, var, w1b, scale, shift);
    k1_gemm_mfma<<<dim3(16, BB), 512, 0, stream>>>(x, w1b, scale, shift, h);
    k2_conv3x3<<<dim3(8, BB), 128, 0, stream>>>(h, w2, b2, score);
    k3_topk_softmax<<<BB, 256, 0, stream>>>(score, weight);
    k4_weighted_sum<<<BB * (CC / 4), 256, 0, stream>>>(x, weight, vout);
}

// Round 7
// 74.087 us; speedup vs baseline: 1.2952x; 1.2952x over previous
//
#include <hip/hip_runtime.h>
#include <math.h>

#define BB 32
#define CC 768
#define HID 96
#define NPIX 1024
#define KSEL 256
#define BN_EPS_F 1e-5f

typedef __bf16 bf16x8 __attribute__((ext_vector_type(8)));
typedef float f32x4 __attribute__((ext_vector_type(4)));

__device__ __forceinline__ unsigned short f2bf(float f) {
    unsigned u = __float_as_uint(f);
    return (unsigned short)((u + 0x7FFFu + ((u >> 16) & 1u)) >> 16);  // RNE
}
__device__ __forceinline__ unsigned pack2(float lo, float hi) {
    return (unsigned)f2bf(lo) | ((unsigned)f2bf(hi) << 16);
}

// ---------------------------------------------------------------------------
// K0: prep — w1 f32 -> bf16 [96][768]; BN scale/shift [96]. grid 73 x 256.
// ---------------------------------------------------------------------------
__global__ __launch_bounds__(256) void k0_prep(
    const float* __restrict__ w1, const float* __restrict__ gamma,
    const float* __restrict__ beta, const float* __restrict__ mean,
    const float* __restrict__ var,
    unsigned short* __restrict__ w1b, float* __restrict__ scale,
    float* __restrict__ shift)
{
    int t = threadIdx.x, bk = blockIdx.x;
    if (bk < 72) {
        int idx = (bk * 256 + t) * 4;
        float4 v = *reinterpret_cast<const float4*>(w1 + idx);
        uint2 o;
        o.x = pack2(v.x, v.y);
        o.y = pack2(v.z, v.w);
        *reinterpret_cast<uint2*>(w1b + idx) = o;
    } else if (t < HID) {
        float sc = gamma[t] * rsqrtf(var[t] + BN_EPS_F);
        scale[t] = sc;
        shift[t] = beta[t] - mean[t] * sc;
    }
}

// ---------------------------------------------------------------------------
// K1 v4: bf16 MFMA GEMM  H[o,n] = sum_c w1[o,c]*x[b,c,n], fused BN+ReLU.
// grid (16 n-tiles of 64, 32 b) = 512 blocks, 512 thr = 8 waves (2 blk/CU).
// Wave (wo,wn) owns 48o x 16n; acc = 3 f32x4.
// W1 in LDS, stride 68 shorts (34 dwords, gcd(34,32)=2 -> conflict-free
// b64-pair fragment reads; fixes R5's 8-way conflict AND R3/R6's
// lane-scattered global W loads). X in LDS pad-66 (conflict-free).
// Both double-buffered; T14 reg prefetch; ONE barrier per chunk.
// ---------------------------------------------------------------------------
__global__ __launch_bounds__(512, 4) void k1_gemm_mfma(
    const float* __restrict__ x, const unsigned short* __restrict__ w1b,
    const float* __restrict__ scale, const float* __restrict__ shift,
    float* __restrict__ h_out)
{
    __shared__ unsigned Xs[2][32][66];          // [buf][kpair][n] uint = 2 bf16
    __shared__ unsigned short Ws[2][96][68];    // [buf][o][k] bf16, stride 68
    __shared__ float sc_s[HID], sh_s[HID];

    const int t = threadIdx.x;
    const int b = blockIdx.y;
    const int n0 = blockIdx.x * 64;
    const int wave = t >> 6, lane = t & 63;
    const int lm = lane & 15, g = lane >> 4;
    const int wo = wave >> 2, wn = wave & 3;
    const int nB = wn * 16 + lm;
    const int kp = t >> 4, q = t & 15;
    const int nc = q * 4;
    const int wrow = t >> 3, wko = (t & 7) * 8;     // W staging map (idx = t)
    const int wrow2 = (t + 512) >> 3, wko2 = wko;   // second W slice (t < 256)

    if (t < HID) { sc_s[t] = scale[t]; sh_s[t] = shift[t]; }

    f32x4 acc[3];
#pragma unroll
    for (int mt = 0; mt < 3; ++mt) acc[mt] = (f32x4){0.f, 0.f, 0.f, 0.f};

    const float* xbase = x + (size_t)b * CC * NPIX + n0;

    // ---- prologue: stage chunk 0 into buf 0 ----
    {
        const float* r0 = xbase + (size_t)(2 * kp) * NPIX;
        float4 a4 = *reinterpret_cast<const float4*>(r0 + nc);
        float4 b4 = *reinterpret_cast<const float4*>(r0 + NPIX + nc);
        uint4 pk;
        pk.x = pack2(a4.x, b4.x); pk.y = pack2(a4.y, b4.y);
        pk.z = pack2(a4.z, b4.z); pk.w = pack2(a4.w, b4.w);
        *reinterpret_cast<uint4*>(&Xs[0][kp][nc]) = pk;

        uint4 w0 = *reinterpret_cast<const uint4*>(w1b + (size_t)wrow * CC + wko);
        *reinterpret_cast<uint4*>(&Ws[0][wrow][wko]) = w0;
        if (t < 256) {
            uint4 w1v = *reinterpret_cast<const uint4*>(w1b + (size_t)wrow2 * CC + wko2);
            *reinterpret_cast<uint4*>(&Ws[0][wrow2][wko2]) = w1v;
        }
    }
    __syncthreads();

    int cur = 0;
#pragma unroll 1
    for (int c0 = 0; c0 < CC; c0 += 64) {
        const bool hasNext = (c0 + 64 < CC);
        // T14: issue next chunk's global loads early
        float4 a4, b4;
        uint4 nw0, nw1;
        if (hasNext) {
            const float* r0 = xbase + (size_t)(c0 + 64 + 2 * kp) * NPIX;
            a4 = *reinterpret_cast<const float4*>(r0 + nc);
            b4 = *reinterpret_cast<const float4*>(r0 + NPIX + nc);
            nw0 = *reinterpret_cast<const uint4*>(
                w1b + (size_t)wrow * CC + c0 + 64 + wko);
            if (t < 256)
                nw1 = *reinterpret_cast<const uint4*>(
                    w1b + (size_t)wrow2 * CC + c0 + 64 + wko2);
        }
        // ---- compute on buf cur: 6 MFMA per wave ----
#pragma unroll
        for (int h = 0; h < 2; ++h) {
            uint4 bu;
            bu.x = Xs[cur][16 * h + 4 * g + 0][nB];
            bu.y = Xs[cur][16 * h + 4 * g + 1][nB];
            bu.z = Xs[cur][16 * h + 4 * g + 2][nB];
            bu.w = Xs[cur][16 * h + 4 * g + 3][nB];
            bf16x8 bfr = __builtin_bit_cast(bf16x8, bu);
#pragma unroll
            for (int mt = 0; mt < 3; ++mt) {
                uint4 au = *reinterpret_cast<const uint4*>(
                    &Ws[cur][wo * 48 + mt * 16 + lm][h * 32 + g * 8]);
                acc[mt] = __builtin_amdgcn_mfma_f32_16x16x32_bf16(
                    __builtin_bit_cast(bf16x8, au), bfr, acc[mt], 0, 0, 0);
            }
        }
        // ---- write next buffer late ----
        if (hasNext) {
            uint4 pk;
            pk.x = pack2(a4.x, b4.x); pk.y = pack2(a4.y, b4.y);
            pk.z = pack2(a4.z, b4.z); pk.w = pack2(a4.w, b4.w);
            *reinterpret_cast<uint4*>(&Xs[cur ^ 1][kp][nc]) = pk;
            *reinterpret_cast<uint4*>(&Ws[cur ^ 1][wrow][wko]) = nw0;
            if (t < 256)
                *reinterpret_cast<uint4*>(&Ws[cur ^ 1][wrow2][wko2]) = nw1;
        }
        __syncthreads();
        cur ^= 1;
    }

    // epilogue: C/D col = lm (n), row = g*4+r (o); BN+ReLU
#pragma unroll
    for (int mt = 0; mt < 3; ++mt) {
#pragma unroll
        for (int r = 0; r < 4; ++r) {
            int o = wo * 48 + mt * 16 + g * 4 + r;
            float v = fmaxf(acc[mt][r] * sc_s[o] + sh_s[o], 0.f);
            h_out[((size_t)b * HID + o) * NPIX + n0 + nB] = v;
        }
    }
}

// ---------------------------------------------------------------------------
// K2: 3x3 conv HID->1, SAME. grid (8 y-tiles of 4 rows, 32 b) = 256 blocks,
// 128 thr (1 px/thread). 16-channel LDS chunks with row halo.
// ---------------------------------------------------------------------------
__global__ __launch_bounds__(128) void k2_conv3x3(
    const float* __restrict__ h_in, const float* __restrict__ w2,
    const float* __restrict__ b2, float* __restrict__ score_out)
{
    __shared__ float hs[16][6][40];   // interior cols 4..35; halo cols 3 and 36
    __shared__ float w2s[HID * 9];

    const int t = threadIdx.x;
    const int ytile = blockIdx.x, b = blockIdx.y;
    const int y = t >> 5, xx = t & 31;
    const int Y = ytile * 4 + y;

    for (int i = t; i < HID * 9; i += 128) w2s[i] = w2[i];

    const float* hb = h_in + (size_t)b * HID * NPIX;
    float acc = 0.f;

    for (int c0 = 0; c0 < HID; c0 += 16) {
        __syncthreads();
        for (int i = t; i < 192; i += 128) {  // zero halo cols (3 and 36)
            int ch = i / 12, rr = (i % 12) >> 1, col = (i & 1) ? 36 : 3;
            hs[ch][rr][col] = 0.f;
        }
#pragma unroll
        for (int i = 0; i < 6; ++i) {
            int idx = t + i * 128;               // 0..767 float4 slots
            int ch = idx / 48, rem = idx % 48;
            int rr = rem >> 3, qq = rem & 7;
            int gy = ytile * 4 - 1 + rr;
            float4 v = (gy >= 0 && gy < 32)
                ? *reinterpret_cast<const float4*>(
                      hb + (size_t)(c0 + ch) * NPIX + gy * 32 + qq * 4)
                : (float4){0.f, 0.f, 0.f, 0.f};
            *reinterpret_cast<float4*>(&hs[ch][rr][4 + qq * 4]) = v;
        }
        __syncthreads();
#pragma unroll
        for (int ch = 0; ch < 16; ++ch) {
            float s = 0.f;
#pragma unroll
            for (int ky = 0; ky < 3; ++ky)
#pragma unroll
                for (int kx = 0; kx < 3; ++kx)
                    s += hs[ch][y + ky][3 + xx + kx] * w2s[(c0 + ch) * 9 + ky * 3 + kx];
            acc += s;
        }
    }
    score_out[b * NPIX + Y * 32 + xx] = acc + b2[0];
}

// ---------------------------------------------------------------------------
// K3: exact top-256 (radix select, first-index tie-break) + softmax ->
// dense weight[1024]. grid 32, 256 thr; elements register-resident (4/thr).
// ---------------------------------------------------------------------------
__global__ __launch_bounds__(256) void k3_topk_softmax(
    const float* __restrict__ score, float* __restrict__ weight)
{
    __shared__ unsigned hist[256];
    __shared__ unsigned wtot[4];
    __shared__ unsigned pcnt16[16];
    __shared__ float redf[4];
    __shared__ unsigned sh_bin, sh_rem;

    const int t = threadIdx.x, b = blockIdx.x;
    const int lane = t & 63, wv = t >> 6;

    float fvals[4];
    unsigned uvals[4];
#pragma unroll
    for (int i = 0; i < 4; ++i) {
        float f = score[b * NPIX + t + 256 * i];
        fvals[i] = f;
        unsigned u = __float_as_uint(f);
        uvals[i] = (u & 0x80000000u) ? ~u : (u | 0x80000000u);
    }

    unsigned prefix = 0, rem = KSEL;
    for (int p = 3; p >= 0; --p) {
        hist[t] = 0;
        __syncthreads();
        const int sh_hi = (p + 1) * 8;
#pragma unroll
        for (int i = 0; i < 4; ++i) {
            unsigned u = uvals[i];
            bool match = (p == 3) || ((u >> sh_hi) == (prefix >> sh_hi));
            if (match) atomicAdd(&hist[(u >> (p * 8)) & 0xffu], 1u);
        }
        __syncthreads();
        unsigned own = hist[t];
        unsigned val = own;
#pragma unroll
        for (int off = 1; off <= 32; off <<= 1) {
            unsigned o2 = __shfl_down(val, off);
            if (lane + off < 64) val += o2;
        }
        if (lane == 0) wtot[wv] = val;
        __syncthreads();
        unsigned suff = val;
        for (int w = wv + 1; w < 4; ++w) suff += wtot[w];
        unsigned nexts = suff - own;        // count with bin > t
        if (suff >= rem && nexts < rem) { sh_bin = (unsigned)t; sh_rem = rem - nexts; }
        __syncthreads();
        prefix |= (sh_bin << (p * 8));
        rem = sh_rem;
        __syncthreads();
    }
    const unsigned T = prefix, need = rem;

    float m = -INFINITY;
#pragma unroll
    for (int i = 0; i < 4; ++i) m = fmaxf(m, fvals[i]);
#pragma unroll
    for (int off = 32; off >= 1; off >>= 1) m = fmaxf(m, __shfl_xor(m, off));
    if (lane == 0) redf[wv] = m;
    __syncthreads();
    m = fmaxf(fmaxf(redf[0], redf[1]), fmaxf(redf[2], redf[3]));

    unsigned lp[4]; bool eqf[4], gtf[4];
    unsigned long long lmask = (1ULL << lane) - 1ULL;
#pragma unroll
    for (int i = 0; i < 4; ++i) {
        bool eq = (uvals[i] == T);
        eqf[i] = eq; gtf[i] = (uvals[i] > T);
        unsigned long long mk = __ballot(eq);
        lp[i] = (unsigned)__popcll(mk & lmask);
        if (lane == 0) pcnt16[i * 4 + wv] = (unsigned)__popcll(mk);
    }
    __syncthreads();
    unsigned cum = 0, baseArr[4];
#pragma unroll
    for (int ii = 0; ii < 4; ++ii) {
        unsigned b0 = cum;
        for (int w = 0; w < wv; ++w) b0 += pcnt16[ii * 4 + w];
        baseArr[ii] = b0;
        for (int w = 0; w < 4; ++w) cum += pcnt16[ii * 4 + w];
    }
    float evals[4], sumExp = 0.f;
#pragma unroll
    for (int i = 0; i < 4; ++i) {
        bool sel = gtf[i] || (eqf[i] && (baseArr[i] + lp[i]) < need);
        float e = sel ? expf(fvals[i] - m) : 0.f;
        evals[i] = e;
        sumExp += e;
    }
#pragma unroll
    for (int off = 32; off >= 1; off >>= 1) sumExp += __shfl_xor(sumExp, off);
    if (lane == 0) redf[wv] = sumExp;
    __syncthreads();
    float inv = 1.0f / (redf[0] + redf[1] + redf[2] + redf[3]);
#pragma unroll
    for (int i = 0; i < 4; ++i)
        weight[b * NPIX + i * 256 + t] = evals[i] * inv;
}

// ---------------------------------------------------------------------------
// K4: v[b,c] = sum_n x[b,c,n]*weight[b,n]. grid 32*192, 4 waves, 1 c/wave.
// ---------------------------------------------------------------------------
__global__ __launch_bounds__(256) void k4_weighted_sum(
    const float* __restrict__ x, const float* __restrict__ weight,
    float* __restrict__ v)
{
    __shared__ float wsm[NPIX];
    const int t = threadIdx.x;
    const int b = blockIdx.x / 192, cg = blockIdx.x % 192;

    *reinterpret_cast<float4*>(&wsm[t * 4]) =
        *reinterpret_cast<const float4*>(&weight[b * NPIX + t * 4]);
    __syncthreads();

    const int lane = t & 63, wvv = t >> 6;
    const int c = cg * 4 + wvv;
    const float* xr = x + ((size_t)b * CC + c) * NPIX;

    float acc = 0.f;
#pragma unroll
    for (int j = 0; j < 4; ++j) {
        int off = j * 256 + lane * 4;
        float4 xv = *reinterpret_cast<const float4*>(xr + off);
        float4 wv4 = *reinterpret_cast<const float4*>(&wsm[off]);
        acc += xv.x * wv4.x + xv.y * wv4.y + xv.z * wv4.z + xv.w * wv4.w;
    }
#pragma unroll
    for (int off = 32; off >= 1; off >>= 1) acc += __shfl_xor(acc, off);
    if (lane == 0) v[(size_t)b * CC + c] = acc;
}

// ---------------------------------------------------------------------------
extern "C" void kernel_launch(void* const* d_in, const int* in_sizes, int n_in,
                              void* d_out, int out_size, void* d_ws, size_t ws_size,
                              hipStream_t stream)
{
    const float* x     = (const float*)d_in[0];
    const float* w1    = (const float*)d_in[1];
    const float* gamma = (const float*)d_in[2];
    const float* beta  = (const float*)d_in[3];
    const float* mean  = (const float*)d_in[4];
    const float* var   = (const float*)d_in[5];
    const float* w2    = (const float*)d_in[6];
    const float* b2    = (const float*)d_in[7];

    float* out   = (float*)d_out;
    float* vout  = out;                  // [32,768]
    float* score = out + BB * CC;        // [32,1024]

    float* h       = (float*)d_ws;                                // 32*96*1024 f32
    float* weight  = h + (size_t)BB * HID * NPIX;                 // 32*1024 f32
    unsigned short* w1b = (unsigned short*)(weight + BB * NPIX);  // 96*768 bf16
    float* scale   = (float*)(w1b + HID * CC);                    // 96
    float* shift   = scale + HID;                                 // 96

    k0_prep<<<73, 256, 0, stream>>>(w1, gamma, beta, mean, var, w1b, scale, shift);
    k1_gemm_mfma<<<dim3(16, BB), 512, 0, stream>>>(x, w1b, scale, shift, h);
    k2_conv3x3<<<dim3(8, BB), 128, 0, stream>>>(h, w2, b2, score);
    k3_topk_softmax<<<BB, 256, 0, stream>>>(score, weight);
    k4_weighted_sum<<<BB * (CC / 4), 256, 0, stream>>>(x, weight, vout);
}